// Round 3
// baseline (95.279 us; speedup 1.0000x reference)
//
#include <hip/hip_runtime.h>

#define HD 32
#define PF 8    // x prefetch depth == inner unroll; T must be a multiple of PF

typedef __attribute__((ext_vector_type(8))) short bf16x8;
typedef __attribute__((ext_vector_type(4))) float f32x4;

__device__ __forceinline__ int cvtpk_bf16(float a, float b) {
    int r;
    asm("v_cvt_pk_bf16_f32 %0, %1, %2" : "=v"(r) : "v"(a), "v"(b));
    return r;  // [bf16(b) | bf16(a)], a in low half
}

// f32 pair -> bf16 hi dword + bf16 residual dword (3-term split precision)
__device__ __forceinline__ void split_pair(float a, float b, int& hi, int& lo) {
    hi = cvtpk_bf16(a, b);
    float fa = __int_as_float(hi << 16);
    float fb = __int_as_float((unsigned)hi & 0xffff0000u);
    lo = cvtpk_bf16(a - fa, b - fb);
}

__device__ __forceinline__ bf16x8 pack4(int w0, int w1, int w2, int w3) {
    union { int i[4]; bf16x8 v; } u;
    u.i[0] = w0; u.i[1] = w1; u.i[2] = w2; u.i[3] = w3;
    return u.v;
}

__device__ __forceinline__ void split_frag(f32x4 a, f32x4 b, bf16x8& hi, bf16x8& lo) {
    int h0,h1,h2,h3,l0,l1,l2,l3;
    split_pair(a[0], a[1], h0, l0);
    split_pair(a[2], a[3], h1, l1);
    split_pair(b[0], b[1], h2, l2);
    split_pair(b[2], b[3], h3, l3);
    hi = pack4(h0,h1,h2,h3);
    lo = pack4(l0,l1,l2,l3);
}

#define MFMA(a,b,c) __builtin_amdgcn_mfma_f32_16x16x32_bf16((a),(b),(c),0,0,0)

// One wave = 16 batches, fully self-contained (no LDS, no barriers).
// MFMA 16x16x32 layouts (validated in round 2): A: lane holds A[m=l&15, k=(l>>4)*8+e];
// B: B[k=(l>>4)*8+e, n=l&15]; D: D[m=(l>>4)*4+r, n=l&15].
// A-row permutation trick: MFMA0 A rows = W[(m>>2)*8+(m&3)], MFMA1 = +4. Then lane (q,c)'s
// D regs hold h_new[q*8+0..7] for batch c == exactly the next step's B fragment. No exchange.
__global__ __launch_bounds__(64, 1)
void rnn_perm(const float* __restrict__ x,
              const float* __restrict__ h0p,
              const float* __restrict__ W_ih,
              const float* __restrict__ W_hh,
              const float* __restrict__ b_ih,
              const float* __restrict__ b_hh,
              const float* __restrict__ W_out,
              const float* __restrict__ b_out,
              float* __restrict__ out,
              int B, int T)
{
    const int l = threadIdx.x;
    const int q = l >> 4;
    const int c = l & 15;
    const int bglob = blockIdx.x * 16 + c;

    // permuted A rows for this lane (lane's A-row index m == c)
    const int rA0 = ((c >> 2) << 3) + (c & 3);
    const int rA1 = rA0 + 4;

    bf16x8 Whh0h, Whh0l, Whh1h, Whh1l, Wih0h, Wih0l, Wih1h, Wih1l;
    {
        const f32x4* p;
        p = (const f32x4*)(W_hh + rA0 * HD + q * 8); split_frag(p[0], p[1], Whh0h, Whh0l);
        p = (const f32x4*)(W_hh + rA1 * HD + q * 8); split_frag(p[0], p[1], Whh1h, Whh1l);
        p = (const f32x4*)(W_ih + rA0 * HD + q * 8); split_frag(p[0], p[1], Wih0h, Wih0l);
        p = (const f32x4*)(W_ih + rA1 * HD + q * 8); split_frag(p[0], p[1], Wih1h, Wih1l);
    }

    // bias in (permuted) D layout: D0 reg r -> unit q*8+r, D1 reg r -> unit q*8+4+r
    f32x4 bias0, bias1;
#pragma unroll
    for (int r = 0; r < 4; ++r) {
        bias0[r] = b_ih[q*8 + r]     + b_hh[q*8 + r];
        bias1[r] = b_ih[q*8 + 4 + r] + b_hh[q*8 + 4 + r];
    }

    // h0 as B fragment: lane needs h[q*8+e, batch c] = 8 contiguous floats
    bf16x8 h_hi, h_lo;
    {
        const f32x4* p = (const f32x4*)(h0p + (size_t)bglob * HD + q * 8);
        split_frag(p[0], p[1], h_hi, h_lo);
    }

    // x as B fragment: lane reads x[bglob, t, q*8 .. q*8+7] = 2 float4
    const f32x4* X4 = (const f32x4*)x + (size_t)bglob * T * (HD / 4) + q * 2;

    f32x4 xa[PF], xb[PF];
#pragma unroll
    for (int k = 0; k < PF; ++k) { xa[k] = X4[(size_t)k * 8]; xb[k] = X4[(size_t)k * 8 + 1]; }

    // xp for t=0
    f32x4 xp0, xp1;
    {
        bf16x8 xh, xl;
        split_frag(xa[0], xb[0], xh, xl);
        xp0 = bias0; xp1 = bias1;
        xp0 = MFMA(Wih0h, xh, xp0); xp1 = MFMA(Wih1h, xh, xp1);
        xp0 = MFMA(Wih0h, xl, xp0); xp1 = MFMA(Wih1h, xl, xp1);
        xp0 = MFMA(Wih0l, xh, xp0); xp1 = MFMA(Wih1l, xh, xp1);
    }

    f32x4 hA = {0,0,0,0}, hB = {0,0,0,0};

    for (int t0 = 0; t0 < T; t0 += PF) {
#pragma unroll
        for (int s = 0; s < PF; ++s) {
            const int t = t0 + s;
            // prefetch x[t+PF] into slot s (consumed PF-1 steps from now)
            if (t + PF < T) {
                xa[s] = X4[(size_t)(t + PF) * 8];
                xb[s] = X4[(size_t)(t + PF) * 8 + 1];
            }
            // recurrence: two independent 3-MFMA chains, C-in = xp (bias folded)
            f32x4 a0 = xp0, a1 = xp1;
            a0 = MFMA(Whh0h, h_hi, a0); a1 = MFMA(Whh1h, h_hi, a1);
            a0 = MFMA(Whh0h, h_lo, a0); a1 = MFMA(Whh1h, h_lo, a1);
            a0 = MFMA(Whh0l, h_hi, a0); a1 = MFMA(Whh1l, h_hi, a1);
            // xp for t+1 (off the serial chain; slot loaded PF-1 steps ago)
            if (t + 1 < T) {
                bf16x8 xh, xl;
                const int sn = (s + 1) & (PF - 1);
                split_frag(xa[sn], xb[sn], xh, xl);
                xp0 = bias0; xp1 = bias1;
                xp0 = MFMA(Wih0h, xh, xp0); xp1 = MFMA(Wih1h, xh, xp1);
                xp0 = MFMA(Wih0h, xl, xp0); xp1 = MFMA(Wih1h, xl, xp1);
                xp0 = MFMA(Wih0l, xh, xp0); xp1 = MFMA(Wih1l, xh, xp1);
            }
            // relu + split-pack: D regs -> next B fragment directly (permutation trick)
#pragma unroll
            for (int r = 0; r < 4; ++r) {
                a0[r] = fmaxf(a0[r], 0.0f);
                a1[r] = fmaxf(a1[r], 0.0f);
            }
            int d0,e0,d1,e1,d2,e2,d3,e3;
            split_pair(a0[0], a0[1], d0, e0);
            split_pair(a0[2], a0[3], d1, e1);
            split_pair(a1[0], a1[1], d2, e2);
            split_pair(a1[2], a1[3], d3, e3);
            h_hi = pack4(d0, d1, d2, d3);
            h_lo = pack4(e0, e1, e2, e3);
            hA = a0; hB = a1;
        }
    }

    // hT: lane holds units q*8+r (hA) and q*8+4+r (hB) of batch c
    float* outh = out + B + (size_t)bglob * HD;
#pragma unroll
    for (int r = 0; r < 4; ++r) {
        outh[q*8 + r]     = hA[r];
        outh[q*8 + 4 + r] = hB[r];
    }
    // pred[b] = sum_j hT[b,j] * W_out[j] + b_out; partials live in lanes {c, c+16, c+32, c+48}
    float p = 0.0f;
#pragma unroll
    for (int r = 0; r < 4; ++r)
        p += hA[r] * W_out[q*8 + r] + hB[r] * W_out[q*8 + 4 + r];
    p += __shfl_xor(p, 16, 64);
    p += __shfl_xor(p, 32, 64);
    if (q == 0) out[bglob] = p + b_out[0];
}

extern "C" void kernel_launch(void* const* d_in, const int* in_sizes, int n_in,
                              void* d_out, int out_size, void* d_ws, size_t ws_size,
                              hipStream_t stream) {
    const float* x      = (const float*)d_in[0];
    const float* hidden = (const float*)d_in[1];
    const float* W_ih   = (const float*)d_in[2];
    const float* W_hh   = (const float*)d_in[3];
    const float* b_ih   = (const float*)d_in[4];
    const float* b_hh   = (const float*)d_in[5];
    const float* W_out  = (const float*)d_in[6];
    const float* b_out  = (const float*)d_in[7];
    float* out = (float*)d_out;

    const int B = in_sizes[1] / HD;          // hidden is (1, B, H)
    const int T = in_sizes[0] / (B * HD);    // x is (B, T, 32)

    rnn_perm<<<dim3(B / 16), dim3(64), 0, stream>>>(
        x, hidden, W_ih, W_hh, b_ih, b_hh, W_out, b_out, out, B, T);
}

// Round 4
// 43.493 us; speedup vs baseline: 2.1907x; 2.1907x over previous
//
#include <hip/hip_runtime.h>

#define HD 32
#define DP 12   // prefetch ring depth; T (=168) must be divisible by DP

typedef __attribute__((ext_vector_type(8))) short bf16x8;
typedef __attribute__((ext_vector_type(4))) float f32x4;

__device__ __forceinline__ int cvtpk_bf16(float a, float b) {
    int r;
    asm("v_cvt_pk_bf16_f32 %0, %1, %2" : "=v"(r) : "v"(a), "v"(b));
    return r;  // [bf16(b) | bf16(a)], a in low half
}

__device__ __forceinline__ void split_pair(float a, float b, int& hi, int& lo) {
    hi = cvtpk_bf16(a, b);
    float fa = __int_as_float(hi << 16);
    float fb = __int_as_float((unsigned)hi & 0xffff0000u);
    lo = cvtpk_bf16(a - fa, b - fb);
}

__device__ __forceinline__ bf16x8 pack4(int w0, int w1, int w2, int w3) {
    union { int i[4]; bf16x8 v; } u;
    u.i[0] = w0; u.i[1] = w1; u.i[2] = w2; u.i[3] = w3;
    return u.v;
}

__device__ __forceinline__ void split_frag(f32x4 a, f32x4 b, bf16x8& hi, bf16x8& lo) {
    int h0,h1,h2,h3,l0,l1,l2,l3;
    split_pair(a[0], a[1], h0, l0);
    split_pair(a[2], a[3], h1, l1);
    split_pair(b[0], b[1], h2, l2);
    split_pair(b[2], b[3], h3, l3);
    hi = pack4(h0,h1,h2,h3);
    lo = pack4(l0,l1,l2,l3);
}

// Forced prefetch: issue point pinned by asm volatile, data regs explicitly held.
__device__ __forceinline__ void gload4(f32x4& dst, const float* p) {
    asm volatile("global_load_dwordx4 %0, %1, off" : "=&v"(dst) : "v"(p));
}

// Counted wait: exactly 2 asm loads issued per step; waiting for the pair issued
// 11 steps ago leaves 22 newer loads in flight. The "+v" ties create true SSA
// deps so no consumer can be scheduled above the wait (rule-#18 safe).
__device__ __forceinline__ void wait22(f32x4& a, f32x4& b) {
    asm volatile("s_waitcnt vmcnt(22)" : "+v"(a), "+v"(b));
}

#define MFMA(a,b,c) __builtin_amdgcn_mfma_f32_16x16x32_bf16((a),(b),(c),0,0,0)

// One wave = 16 batches, no LDS, no barriers. MFMA 16x16x32 layouts (validated r2/r3):
// A: lane(q,c) holds A[m=c, k=q*8+e]; B: B[k=q*8+e, n=c]; D: D[m=q*4+r, n=c].
// A-row permutation trick: MFMA0 A rows = W[(m>>2)*8+(m&3)], MFMA1 = +4, so lane (q,c)'s
// D regs hold h_new[q*8+0..7] of batch c == exactly the next step's B fragment in-place.
__global__ __launch_bounds__(64, 1)
void rnn_pipe(const float* __restrict__ x,
              const float* __restrict__ h0p,
              const float* __restrict__ W_ih,
              const float* __restrict__ W_hh,
              const float* __restrict__ b_ih,
              const float* __restrict__ b_hh,
              const float* __restrict__ W_out,
              const float* __restrict__ b_out,
              float* __restrict__ out,
              int B, int T)
{
    const int l = threadIdx.x;
    const int q = l >> 4;
    const int c = l & 15;
    const int bglob = blockIdx.x * 16 + c;

    const int rA0 = ((c >> 2) << 3) + (c & 3);   // permuted A-row for MFMA0
    const int rA1 = rA0 + 4;                      // for MFMA1

    bf16x8 Whh0h, Whh0l, Whh1h, Whh1l, Wih0h, Wih0l, Wih1h, Wih1l;
    {
        const f32x4* p;
        p = (const f32x4*)(W_hh + rA0 * HD + q * 8); split_frag(p[0], p[1], Whh0h, Whh0l);
        p = (const f32x4*)(W_hh + rA1 * HD + q * 8); split_frag(p[0], p[1], Whh1h, Whh1l);
        p = (const f32x4*)(W_ih + rA0 * HD + q * 8); split_frag(p[0], p[1], Wih0h, Wih0l);
        p = (const f32x4*)(W_ih + rA1 * HD + q * 8); split_frag(p[0], p[1], Wih1h, Wih1l);
    }

    f32x4 bias0, bias1;
#pragma unroll
    for (int r = 0; r < 4; ++r) {
        bias0[r] = b_ih[q*8 + r]     + b_hh[q*8 + r];
        bias1[r] = b_ih[q*8 + 4 + r] + b_hh[q*8 + 4 + r];
    }

    bf16x8 h_hi, h_lo;
    {
        const f32x4* p = (const f32x4*)(h0p + (size_t)bglob * HD + q * 8);
        split_frag(p[0], p[1], h_hi, h_lo);
    }

    // x: lane reads x[bglob, t, q*8 .. q*8+7] as two dwordx4
    const float* base = x + (size_t)bglob * T * HD + q * 8;

    f32x4 xa[DP], xb[DP];
    // prologue: fill the ring (24 loads in flight)
#pragma unroll
    for (int s = 0; s < DP; ++s) {
        gload4(xa[s], base + (size_t)s * HD);
        gload4(xb[s], base + (size_t)s * HD + 4);
    }

    // xp(0): wait slot 0 (issues 1,2 of 24 -> 22 newer in flight)
    f32x4 xp0, xp1;
    {
        wait22(xa[0], xb[0]);
        bf16x8 xh, xl;
        split_frag(xa[0], xb[0], xh, xl);
        xp0 = MFMA(Wih0h, xh, bias0);
        xp0 = MFMA(Wih0h, xl, xp0);
        xp0 = MFMA(Wih0l, xh, xp0);
        xp1 = MFMA(Wih1h, xh, bias1);
        xp1 = MFMA(Wih1h, xl, xp1);
        xp1 = MFMA(Wih1l, xh, xp1);
    }

    f32x4 hA = {0,0,0,0}, hB = {0,0,0,0};

    for (int t0 = 0; t0 < T; t0 += DP) {
#pragma unroll
        for (int s = 0; s < DP; ++s) {
            const int t = t0 + s;
            // refill slot s with x[t+DP] (clamped; always exactly 2 loads/step)
            int k = t + DP; k = (k < T) ? k : (T - 1);
            gload4(xa[s], base + (size_t)k * HD);
            gload4(xb[s], base + (size_t)k * HD + 4);

            // recurrence: two parallel chains (1-deep and 2-deep), C-in = xp
            f32x4 a0 = MFMA(Whh0h, h_hi, xp0);
            f32x4 a1 = MFMA(Whh1h, h_hi, xp1);
            f32x4 z = {0.0f, 0.0f, 0.0f, 0.0f};
            f32x4 c0 = MFMA(Whh0h, h_lo, z);
            c0 = MFMA(Whh0l, h_hi, c0);
            f32x4 c1 = MFMA(Whh1h, h_lo, z);
            c1 = MFMA(Whh1l, h_hi, c1);

            // xp for t+1 (slot loaded 11 steps ago; off the serial h-chain)
            const int sn = (s + 1 < DP) ? s + 1 : 0;
            wait22(xa[sn], xb[sn]);
            bf16x8 xh, xl;
            split_frag(xa[sn], xb[sn], xh, xl);
            xp0 = MFMA(Wih0h, xh, bias0);
            xp0 = MFMA(Wih0h, xl, xp0);
            xp0 = MFMA(Wih0l, xh, xp0);
            xp1 = MFMA(Wih1h, xh, bias1);
            xp1 = MFMA(Wih1h, xl, xp1);
            xp1 = MFMA(Wih1l, xh, xp1);

            // join + relu + split-pack: D regs become next B fragment directly
            a0 = a0 + c0;
            a1 = a1 + c1;
#pragma unroll
            for (int r = 0; r < 4; ++r) {
                a0[r] = fmaxf(a0[r], 0.0f);
                a1[r] = fmaxf(a1[r], 0.0f);
            }
            int d0,e0,d1,e1,d2,e2,d3,e3;
            split_pair(a0[0], a0[1], d0, e0);
            split_pair(a0[2], a0[3], d1, e1);
            split_pair(a1[0], a1[1], d2, e2);
            split_pair(a1[2], a1[3], d3, e3);
            h_hi = pack4(d0, d1, d2, d3);
            h_lo = pack4(e0, e1, e2, e3);
            hA = a0; hB = a1;
        }
    }

    // hT: lane holds units q*8+r (hA) and q*8+4+r (hB) of batch c
    float* outh = out + B + (size_t)bglob * HD;
#pragma unroll
    for (int r = 0; r < 4; ++r) {
        outh[q*8 + r]     = hA[r];
        outh[q*8 + 4 + r] = hB[r];
    }
    // pred[b]: partials in lanes {c, c+16, c+32, c+48}
    float p = 0.0f;
#pragma unroll
    for (int r = 0; r < 4; ++r)
        p += hA[r] * W_out[q*8 + r] + hB[r] * W_out[q*8 + 4 + r];
    p += __shfl_xor(p, 16, 64);
    p += __shfl_xor(p, 32, 64);
    if (q == 0) out[bglob] = p + b_out[0];
}

extern "C" void kernel_launch(void* const* d_in, const int* in_sizes, int n_in,
                              void* d_out, int out_size, void* d_ws, size_t ws_size,
                              hipStream_t stream) {
    const float* x      = (const float*)d_in[0];
    const float* hidden = (const float*)d_in[1];
    const float* W_ih   = (const float*)d_in[2];
    const float* W_hh   = (const float*)d_in[3];
    const float* b_ih   = (const float*)d_in[4];
    const float* b_hh   = (const float*)d_in[5];
    const float* W_out  = (const float*)d_in[6];
    const float* b_out  = (const float*)d_in[7];
    float* out = (float*)d_out;

    const int B = in_sizes[1] / HD;          // hidden is (1, B, H)
    const int T = in_sizes[0] / (B * HD);    // x is (B, T, 32); T=168 = 14*DP

    rnn_pipe<<<dim3(B / 16), dim3(64), 0, stream>>>(
        x, hidden, W_ih, W_hh, b_ih, b_hh, W_out, b_out, out, B, T);
}

// Round 5
// 34.047 us; speedup vs baseline: 2.7985x; 1.2774x over previous
//
#include <hip/hip_runtime.h>

#define HD 32
#define DP 12    // x prefetch ring depth; T (=168) divisible by DP
#define LOOKB 2  // xp computed LOOKB steps ahead (parity ring => must be 2)

typedef __attribute__((ext_vector_type(8))) short bf16x8;
typedef __attribute__((ext_vector_type(4))) float f32x4;

__device__ __forceinline__ int cvtpk_bf16(float a, float b) {
    int r;
    asm("v_cvt_pk_bf16_f32 %0, %1, %2" : "=v"(r) : "v"(a), "v"(b));
    return r;  // [bf16(b) | bf16(a)], a in low half
}

__device__ __forceinline__ void split_pair(float a, float b, int& hi, int& lo) {
    hi = cvtpk_bf16(a, b);
    float fa = __int_as_float(hi << 16);
    float fb = __int_as_float((unsigned)hi & 0xffff0000u);
    lo = cvtpk_bf16(a - fa, b - fb);
}

__device__ __forceinline__ bf16x8 pack4(int w0, int w1, int w2, int w3) {
    union { int i[4]; bf16x8 v; } u;
    u.i[0] = w0; u.i[1] = w1; u.i[2] = w2; u.i[3] = w3;
    return u.v;
}

__device__ __forceinline__ void split_frag(f32x4 a, f32x4 b, bf16x8& hi, bf16x8& lo) {
    int h0,h1,h2,h3,l0,l1,l2,l3;
    split_pair(a[0], a[1], h0, l0);
    split_pair(a[2], a[3], h1, l1);
    split_pair(b[0], b[1], h2, l2);
    split_pair(b[2], b[3], h3, l3);
    hi = pack4(h0,h1,h2,h3);
    lo = pack4(l0,l1,l2,l3);
}

// Scalar-base + per-lane voffset loads: uniform time offset lives in the SGPR
// base (SALU increments), lane-constant byte offset in one VGPR. xb via offset:16.
__device__ __forceinline__ void gload_pair(f32x4& a, f32x4& b, const float* sbase, int voff) {
    asm volatile("global_load_dwordx4 %0, %2, %3\n\t"
                 "global_load_dwordx4 %1, %2, %3 offset:16"
                 : "=&v"(a), "=&v"(b) : "v"(voff), "s"(sbase));
}

// Counted waits; "+v" ties give consumers a true SSA dep on the wait (rule-#18 safe).
#define WAIT_TIE(N, a, b) asm volatile("s_waitcnt vmcnt(" #N ")" : "+v"(a), "+v"(b))

#define MFMA(a,b,c) __builtin_amdgcn_mfma_f32_16x16x32_bf16((a),(b),(c),0,0,0)

// One wave = 16 batches, no LDS, no barriers. MFMA 16x16x32 layouts (validated r2-r4):
// A: lane(q,c) holds A[m=c, k=q*8+e]; B: B[k=q*8+e, n=c]; D: D[m=q*4+r, n=c].
// A-row permutation trick: MFMA0 A rows = W[(m>>2)*8+(m&3)], MFMA1 = +4, so lane (q,c)'s
// D regs hold h_new[q*8+0..7] of batch c == exactly the next step's B fragment in-place.
__global__ __launch_bounds__(64, 1)
void rnn_v5(const float* __restrict__ x,
            const float* __restrict__ h0p,
            const float* __restrict__ W_ih,
            const float* __restrict__ W_hh,
            const float* __restrict__ b_ih,
            const float* __restrict__ b_hh,
            const float* __restrict__ W_out,
            const float* __restrict__ b_out,
            float* __restrict__ out,
            int B, int T)
{
    const int l = threadIdx.x;
    const int q = l >> 4;
    const int c = l & 15;
    const int bglob = blockIdx.x * 16 + c;

    const int rA0 = ((c >> 2) << 3) + (c & 3);   // permuted A-row for MFMA0
    const int rA1 = rA0 + 4;                      // for MFMA1

    bf16x8 Whh0h, Whh0l, Whh1h, Whh1l, Wih0h, Wih0l, Wih1h, Wih1l;
    {
        const f32x4* p;
        p = (const f32x4*)(W_hh + rA0 * HD + q * 8); split_frag(p[0], p[1], Whh0h, Whh0l);
        p = (const f32x4*)(W_hh + rA1 * HD + q * 8); split_frag(p[0], p[1], Whh1h, Whh1l);
        p = (const f32x4*)(W_ih + rA0 * HD + q * 8); split_frag(p[0], p[1], Wih0h, Wih0l);
        p = (const f32x4*)(W_ih + rA1 * HD + q * 8); split_frag(p[0], p[1], Wih1h, Wih1l);
    }

    f32x4 bias0, bias1;
#pragma unroll
    for (int r = 0; r < 4; ++r) {
        bias0[r] = b_ih[q*8 + r]     + b_hh[q*8 + r];
        bias1[r] = b_ih[q*8 + 4 + r] + b_hh[q*8 + 4 + r];
    }

    // h0 -> plain bf16 B fragment (one-time 2^-9 rounding)
    bf16x8 h_bf;
    {
        const f32x4* p = (const f32x4*)(h0p + (size_t)bglob * HD + q * 8);
        f32x4 a = p[0], b = p[1];
        h_bf = pack4(cvtpk_bf16(a[0], a[1]), cvtpk_bf16(a[2], a[3]),
                     cvtpk_bf16(b[0], b[1]), cvtpk_bf16(b[2], b[3]));
    }

    // lane-constant byte offset; time offset goes in the scalar base
    const int voff = (int)(((size_t)bglob * T * HD + q * 8) * 4);

    f32x4 xa[DP], xb[DP];
#pragma unroll
    for (int s = 0; s < DP; ++s)
        gload_pair(xa[s], xb[s], x + (size_t)s * HD, voff);

    // xp(0) and xp(1) (parity ring: xpA = even t, xpB = odd t)
    f32x4 xpA0, xpA1, xpB0, xpB1;
    {
        WAIT_TIE(22, xa[0], xb[0]);
        bf16x8 xh, xl;
        split_frag(xa[0], xb[0], xh, xl);
        xpA0 = MFMA(Wih0h, xh, bias0);
        xpA0 = MFMA(Wih0h, xl, xpA0);
        xpA0 = MFMA(Wih0l, xh, xpA0);
        xpA1 = MFMA(Wih1h, xh, bias1);
        xpA1 = MFMA(Wih1h, xl, xpA1);
        xpA1 = MFMA(Wih1l, xh, xpA1);
    }
    {
        WAIT_TIE(20, xa[1], xb[1]);
        bf16x8 xh, xl;
        split_frag(xa[1], xb[1], xh, xl);
        xpB0 = MFMA(Wih0h, xh, bias0);
        xpB0 = MFMA(Wih0h, xl, xpB0);
        xpB0 = MFMA(Wih0l, xh, xpB0);
        xpB1 = MFMA(Wih1h, xh, bias1);
        xpB1 = MFMA(Wih1h, xl, xpB1);
        xpB1 = MFMA(Wih1l, xh, xpB1);
    }

    f32x4 hA = {0,0,0,0}, hB = {0,0,0,0};

    for (int t0 = 0; t0 < T; t0 += DP) {
#pragma unroll
        for (int s = 0; s < DP; ++s) {
            const int t = t0 + s;
            // refill slot s with x[t+DP] (clamped; exactly one load pair per step)
            int k = t + DP; k = (k < T) ? k : (T - 1);
            gload_pair(xa[s], xb[s], x + (size_t)k * HD, voff);

            // recurrence: two independent 2-deep C-chained MFMA chains (fast C-forwarding)
            f32x4 a0, a1;
            if ((s & 1) == 0) {
                a0 = MFMA(Whh0h, h_bf, xpA0);
                a1 = MFMA(Whh1h, h_bf, xpA1);
            } else {
                a0 = MFMA(Whh0h, h_bf, xpB0);
                a1 = MFMA(Whh1h, h_bf, xpB1);
            }
            a0 = MFMA(Whh0l, h_bf, a0);
            a1 = MFMA(Whh1l, h_bf, a1);

            // xp(t+2) into the same-parity slot (consumed 2 steps from now; off-chain)
            {
                const int sx = (s + LOOKB) % DP;    // holds x[t+2]
                WAIT_TIE(20, xa[sx], xb[sx]);
                bf16x8 xh, xl;
                split_frag(xa[sx], xb[sx], xh, xl);
                if ((s & 1) == 0) {
                    xpA0 = MFMA(Wih0h, xh, bias0);
                    xpA0 = MFMA(Wih0h, xl, xpA0);
                    xpA0 = MFMA(Wih0l, xh, xpA0);
                    xpA1 = MFMA(Wih1h, xh, bias1);
                    xpA1 = MFMA(Wih1h, xl, xpA1);
                    xpA1 = MFMA(Wih1l, xh, xpA1);
                } else {
                    xpB0 = MFMA(Wih0h, xh, bias0);
                    xpB0 = MFMA(Wih0h, xl, xpB0);
                    xpB0 = MFMA(Wih0l, xh, xpB0);
                    xpB1 = MFMA(Wih1h, xh, bias1);
                    xpB1 = MFMA(Wih1h, xl, xpB1);
                    xpB1 = MFMA(Wih1l, xh, xpB1);
                }
            }

            // relu + pack: D regs become the next step's B fragment directly
#pragma unroll
            for (int r = 0; r < 4; ++r) {
                a0[r] = fmaxf(a0[r], 0.0f);
                a1[r] = fmaxf(a1[r], 0.0f);
            }
            h_bf = pack4(cvtpk_bf16(a0[0], a0[1]), cvtpk_bf16(a0[2], a0[3]),
                         cvtpk_bf16(a1[0], a1[1]), cvtpk_bf16(a1[2], a1[3]));
            hA = a0; hB = a1;
        }
    }

    // hT: lane holds units q*8+r (hA) and q*8+4+r (hB) of batch c
    float* outh = out + B + (size_t)bglob * HD;
#pragma unroll
    for (int r = 0; r < 4; ++r) {
        outh[q*8 + r]     = hA[r];
        outh[q*8 + 4 + r] = hB[r];
    }
    // pred[b]: partials in lanes {c, c+16, c+32, c+48}
    float p = 0.0f;
#pragma unroll
    for (int r = 0; r < 4; ++r)
        p += hA[r] * W_out[q*8 + r] + hB[r] * W_out[q*8 + 4 + r];
    p += __shfl_xor(p, 16, 64);
    p += __shfl_xor(p, 32, 64);
    if (q == 0) out[bglob] = p + b_out[0];
}

extern "C" void kernel_launch(void* const* d_in, const int* in_sizes, int n_in,
                              void* d_out, int out_size, void* d_ws, size_t ws_size,
                              hipStream_t stream) {
    const float* x      = (const float*)d_in[0];
    const float* hidden = (const float*)d_in[1];
    const float* W_ih   = (const float*)d_in[2];
    const float* W_hh   = (const float*)d_in[3];
    const float* b_ih   = (const float*)d_in[4];
    const float* b_hh   = (const float*)d_in[5];
    const float* W_out  = (const float*)d_in[6];
    const float* b_out  = (const float*)d_in[7];
    float* out = (float*)d_out;

    const int B = in_sizes[1] / HD;          // hidden is (1, B, H)
    const int T = in_sizes[0] / (B * HD);    // x is (B, T, 32); T=168 = 14*DP

    rnn_v5<<<dim3(B / 16), dim3(64), 0, stream>>>(
        x, hidden, W_ih, W_hh, b_ih, b_hh, W_out, b_out, out, B, T);
}

// Round 6
// 27.384 us; speedup vs baseline: 3.4793x; 1.2433x over previous
//
#include <hip/hip_runtime.h>

#define HD 32
#define DP 8     // x prefetch ring depth == inner unroll; T (=168) divisible by DP

typedef __attribute__((ext_vector_type(8))) short bf16x8;
typedef __attribute__((ext_vector_type(4))) float f32x4;

__device__ __forceinline__ int cvtpk_bf16(float a, float b) {
    int r;
    asm("v_cvt_pk_bf16_f32 %0, %1, %2" : "=v"(r) : "v"(a), "v"(b));
    return r;  // [bf16(b) | bf16(a)], a in low half
}

__device__ __forceinline__ void split_pair(float a, float b, int& hi, int& lo) {
    hi = cvtpk_bf16(a, b);
    float fa = __int_as_float(hi << 16);
    float fb = __int_as_float((unsigned)hi & 0xffff0000u);
    lo = cvtpk_bf16(a - fa, b - fb);
}

__device__ __forceinline__ bf16x8 pack4(int w0, int w1, int w2, int w3) {
    union { int i[4]; bf16x8 v; } u;
    u.i[0] = w0; u.i[1] = w1; u.i[2] = w2; u.i[3] = w3;
    return u.v;
}

// weights only: f32x4 pair -> split bf16 fragments (hi + residual)
__device__ __forceinline__ void split_frag(f32x4 a, f32x4 b, bf16x8& hi, bf16x8& lo) {
    int h0,h1,h2,h3,l0,l1,l2,l3;
    split_pair(a[0], a[1], h0, l0);
    split_pair(a[2], a[3], h1, l1);
    split_pair(b[0], b[1], h2, l2);
    split_pair(b[2], b[3], h3, l3);
    hi = pack4(h0,h1,h2,h3);
    lo = pack4(l0,l1,l2,l3);
}

// x: plain bf16 fragment (4 cvt_pk; error feeds xp only, non-compounding)
__device__ __forceinline__ bf16x8 to_bf16_frag(f32x4 a, f32x4 b) {
    return pack4(cvtpk_bf16(a[0], a[1]), cvtpk_bf16(a[2], a[3]),
                 cvtpk_bf16(b[0], b[1]), cvtpk_bf16(b[2], b[3]));
}

// Forced prefetch: SGPR base carries the (uniform) time offset, lane-constant
// byte offset in one VGPR; issue point pinned by asm volatile.
__device__ __forceinline__ void gload_pair(f32x4& a, f32x4& b, const float* sbase, int voff) {
    asm volatile("global_load_dwordx4 %0, %2, %3\n\t"
                 "global_load_dwordx4 %1, %2, %3 offset:16"
                 : "=&v"(a), "=&v"(b) : "v"(voff), "s"(sbase));
}

// Counted waits; "+v" ties give consumers true SSA deps on the wait (rule-#18 safe).
#define WAIT_TIE2(N, a, b) \
    asm volatile("s_waitcnt vmcnt(" #N ")" : "+v"(a), "+v"(b))
#define WAIT_TIE4(N, a, b, c, d) \
    asm volatile("s_waitcnt vmcnt(" #N ")" : "+v"(a), "+v"(b), "+v"(c), "+v"(d))

#define MFMA(a,b,c) __builtin_amdgcn_mfma_f32_16x16x32_bf16((a),(b),(c),0,0,0)

// One wave = 16 batches, no LDS, no barriers. MFMA 16x16x32 layouts (validated r2-r5):
// A: lane(q,c) holds A[m=c, k=q*8+e]; B: B[k=q*8+e, n=c]; D: D[m=q*4+r, n=c].
// A-row permutation trick: MFMA0 A rows = W[(m>>2)*8+(m&3)], MFMA1 = +4, so lane (q,c)'s
// D regs hold h_new[q*8+0..7] of batch c == exactly the next step's B fragment in-place.
__global__ __launch_bounds__(64, 1)
void rnn_v6(const float* __restrict__ x,
            const float* __restrict__ h0p,
            const float* __restrict__ W_ih,
            const float* __restrict__ W_hh,
            const float* __restrict__ b_ih,
            const float* __restrict__ b_hh,
            const float* __restrict__ W_out,
            const float* __restrict__ b_out,
            float* __restrict__ out,
            int B, int T)
{
    const int l = threadIdx.x;
    const int q = l >> 4;
    const int c = l & 15;
    const int bglob = blockIdx.x * 16 + c;

    const int rA0 = ((c >> 2) << 3) + (c & 3);   // permuted A-row for MFMA0
    const int rA1 = rA0 + 4;                      // for MFMA1

    bf16x8 Whh0h, Whh0l, Whh1h, Whh1l, Wih0h, Wih0l, Wih1h, Wih1l;
    {
        const f32x4* p;
        p = (const f32x4*)(W_hh + rA0 * HD + q * 8); split_frag(p[0], p[1], Whh0h, Whh0l);
        p = (const f32x4*)(W_hh + rA1 * HD + q * 8); split_frag(p[0], p[1], Whh1h, Whh1l);
        p = (const f32x4*)(W_ih + rA0 * HD + q * 8); split_frag(p[0], p[1], Wih0h, Wih0l);
        p = (const f32x4*)(W_ih + rA1 * HD + q * 8); split_frag(p[0], p[1], Wih1h, Wih1l);
    }

    f32x4 bias0, bias1;
#pragma unroll
    for (int r = 0; r < 4; ++r) {
        bias0[r] = b_ih[q*8 + r]     + b_hh[q*8 + r];
        bias1[r] = b_ih[q*8 + 4 + r] + b_hh[q*8 + 4 + r];
    }

    // h0 -> plain bf16 B fragment (one-time rounding)
    bf16x8 h_bf;
    {
        const f32x4* p = (const f32x4*)(h0p + (size_t)bglob * HD + q * 8);
        f32x4 a = p[0], b = p[1];
        h_bf = to_bf16_frag(a, b);
    }

    // lane-constant byte offset; uniform time offset lives in the SGPR base
    const int voff = (int)(((size_t)bglob * T * HD + q * 8) * 4);

    f32x4 xa[DP], xb[DP];
#pragma unroll
    for (int s = 0; s < DP; ++s)
        gload_pair(xa[s], xb[s], x + (size_t)s * HD, voff);

    // xp parity ring: xpA = next even step, xpB = next odd step
    f32x4 xpA0, xpA1, xpB0, xpB1;
    {
        WAIT_TIE2(14, xa[0], xb[0]);                  // 16 issued, complete pair 0
        bf16x8 xbf = to_bf16_frag(xa[0], xb[0]);
        xpA0 = MFMA(Wih0h, xbf, bias0);
        xpA1 = MFMA(Wih1h, xbf, bias1);
        xpA0 = MFMA(Wih0l, xbf, xpA0);
        xpA1 = MFMA(Wih1l, xbf, xpA1);
    }
    {
        WAIT_TIE2(12, xa[1], xb[1]);                  // complete pair 1
        bf16x8 xbf = to_bf16_frag(xa[1], xb[1]);
        xpB0 = MFMA(Wih0h, xbf, bias0);
        xpB1 = MFMA(Wih1h, xbf, bias1);
        xpB0 = MFMA(Wih0l, xbf, xpB0);
        xpB1 = MFMA(Wih1l, xbf, xpB1);
    }

    f32x4 hA = {0,0,0,0}, hB = {0,0,0,0};

    // Steady-state ledger (per 2-step group at even t): entering with 12 loads
    // (pairs x[t+2..t+7]) outstanding; issue pairs x[t+8],x[t+9] -> 16; wait
    // vmcnt(12) completes pairs x[t+2],x[t+3]. Lookahead 6 steps >> HBM latency.
    for (int t0 = 0; t0 < T; t0 += DP) {
#pragma unroll
        for (int s = 0; s < DP; s += 2) {
            const int t = t0 + s;                     // even
            // ---- recurrence for step t (chain head; consumes xpA) ----
            f32x4 a0 = MFMA(Whh0h, h_bf, xpA0);
            f32x4 a1 = MFMA(Whh1h, h_bf, xpA1);
            a0 = MFMA(Whh0l, h_bf, a0);
            a1 = MFMA(Whh1l, h_bf, a1);

            // ---- refill ring slots s, s+1 with x[t+8], x[t+9] (clamped) ----
            int k1 = t + DP;     k1 = (k1 < T) ? k1 : (T - 1);
            int k2 = t + DP + 1; k2 = (k2 < T) ? k2 : (T - 1);
            gload_pair(xa[s],     xb[s],     x + (size_t)k1 * HD, voff);
            gload_pair(xa[s + 1], xb[s + 1], x + (size_t)k2 * HD, voff);

            // ---- wait for x[t+2], x[t+3] ----
            const int s2 = (s + 2) & (DP - 1);
            const int s3 = (s + 3) & (DP - 1);
            WAIT_TIE4(12, xa[s2], xb[s2], xa[s3], xb[s3]);

            // ---- xp(t+2) into xpA (off-chain; 2 steps of slack) ----
            {
                bf16x8 xbf = to_bf16_frag(xa[s2], xb[s2]);
                xpA0 = MFMA(Wih0h, xbf, bias0);
                xpA1 = MFMA(Wih1h, xbf, bias1);
                xpA0 = MFMA(Wih0l, xbf, xpA0);
                xpA1 = MFMA(Wih1l, xbf, xpA1);
            }

            // ---- finish step t: relu + pack -> h_bf(t+1) ----
#pragma unroll
            for (int r = 0; r < 4; ++r) {
                a0[r] = fmaxf(a0[r], 0.0f);
                a1[r] = fmaxf(a1[r], 0.0f);
            }
            h_bf = pack4(cvtpk_bf16(a0[0], a0[1]), cvtpk_bf16(a0[2], a0[3]),
                         cvtpk_bf16(a1[0], a1[1]), cvtpk_bf16(a1[2], a1[3]));

            // ---- recurrence for step t+1 (consumes xpB) ----
            f32x4 b0 = MFMA(Whh0h, h_bf, xpB0);
            f32x4 b1 = MFMA(Whh1h, h_bf, xpB1);
            b0 = MFMA(Whh0l, h_bf, b0);
            b1 = MFMA(Whh1l, h_bf, b1);

            // ---- xp(t+3) into xpB ----
            {
                bf16x8 xbf = to_bf16_frag(xa[s3], xb[s3]);
                xpB0 = MFMA(Wih0h, xbf, bias0);
                xpB1 = MFMA(Wih1h, xbf, bias1);
                xpB0 = MFMA(Wih0l, xbf, xpB0);
                xpB1 = MFMA(Wih1l, xbf, xpB1);
            }

            // ---- finish step t+1 ----
#pragma unroll
            for (int r = 0; r < 4; ++r) {
                b0[r] = fmaxf(b0[r], 0.0f);
                b1[r] = fmaxf(b1[r], 0.0f);
            }
            h_bf = pack4(cvtpk_bf16(b0[0], b0[1]), cvtpk_bf16(b0[2], b0[3]),
                         cvtpk_bf16(b1[0], b1[1]), cvtpk_bf16(b1[2], b1[3]));
            hA = b0; hB = b1;
        }
    }

    // hT: lane holds units q*8+r (hA) and q*8+4+r (hB) of batch c
    float* outh = out + B + (size_t)bglob * HD;
#pragma unroll
    for (int r = 0; r < 4; ++r) {
        outh[q*8 + r]     = hA[r];
        outh[q*8 + 4 + r] = hB[r];
    }
    // pred[b]: partials in lanes {c, c+16, c+32, c+48}
    float p = 0.0f;
#pragma unroll
    for (int r = 0; r < 4; ++r)
        p += hA[r] * W_out[q*8 + r] + hB[r] * W_out[q*8 + 4 + r];
    p += __shfl_xor(p, 16, 64);
    p += __shfl_xor(p, 32, 64);
    if (q == 0) out[bglob] = p + b_out[0];
}

extern "C" void kernel_launch(void* const* d_in, const int* in_sizes, int n_in,
                              void* d_out, int out_size, void* d_ws, size_t ws_size,
                              hipStream_t stream) {
    const float* x      = (const float*)d_in[0];
    const float* hidden = (const float*)d_in[1];
    const float* W_ih   = (const float*)d_in[2];
    const float* W_hh   = (const float*)d_in[3];
    const float* b_ih   = (const float*)d_in[4];
    const float* b_hh   = (const float*)d_in[5];
    const float* W_out  = (const float*)d_in[6];
    const float* b_out  = (const float*)d_in[7];
    float* out = (float*)d_out;

    const int B = in_sizes[1] / HD;          // hidden is (1, B, H)
    const int T = in_sizes[0] / (B * HD);    // x is (B, T, 32); T=168 = 21*DP

    rnn_v6<<<dim3(B / 16), dim3(64), 0, stream>>>(
        x, hidden, W_ih, W_hh, b_ih, b_hh, W_out, b_out, out, B, T);
}

// Round 7
// 23.421 us; speedup vs baseline: 4.0681x; 1.1692x over previous
//
#include <hip/hip_runtime.h>

#define HD 32
#define DP 12    // x prefetch ring depth; T (=168) divisible by DP

typedef __attribute__((ext_vector_type(8))) short bf16x8;
typedef __attribute__((ext_vector_type(4))) float f32x4;

__device__ __forceinline__ int cvtpk_bf16(float a, float b) {
    int r;
    asm("v_cvt_pk_bf16_f32 %0, %1, %2" : "=v"(r) : "v"(a), "v"(b));
    return r;  // [bf16(b) | bf16(a)], a in low half
}

__device__ __forceinline__ void split_pair(float a, float b, int& hi, int& lo) {
    hi = cvtpk_bf16(a, b);
    float fa = __int_as_float(hi << 16);
    float fb = __int_as_float((unsigned)hi & 0xffff0000u);
    lo = cvtpk_bf16(a - fa, b - fb);
}

__device__ __forceinline__ bf16x8 pack4(int w0, int w1, int w2, int w3) {
    union { int i[4]; bf16x8 v; } u;
    u.i[0] = w0; u.i[1] = w1; u.i[2] = w2; u.i[3] = w3;
    return u.v;
}

// weights (W_hh only): f32x4 pair -> split bf16 fragments (hi + residual)
__device__ __forceinline__ void split_frag(f32x4 a, f32x4 b, bf16x8& hi, bf16x8& lo) {
    int h0,h1,h2,h3,l0,l1,l2,l3;
    split_pair(a[0], a[1], h0, l0);
    split_pair(a[2], a[3], h1, l1);
    split_pair(b[0], b[1], h2, l2);
    split_pair(b[2], b[3], h3, l3);
    hi = pack4(h0,h1,h2,h3);
    lo = pack4(l0,l1,l2,l3);
}

// plain bf16 fragment (RNE)
__device__ __forceinline__ bf16x8 to_bf16_frag(f32x4 a, f32x4 b) {
    return pack4(cvtpk_bf16(a[0], a[1]), cvtpk_bf16(a[2], a[3]),
                 cvtpk_bf16(b[0], b[1]), cvtpk_bf16(b[2], b[3]));
}

// relu on a packed bf16 pair: sign-monotonic 16-bit compare vs +0 is exact for
// |x| < 2^121 (bf16 patterns never hit the f16 inf/NaN exponent range here).
__device__ __forceinline__ int pk_relu(int v) {
    int r;
    asm("v_pk_max_f16 %0, %1, 0" : "=v"(r) : "v"(v));
    return r;
}

// Forced prefetch: SGPR base carries the (uniform) time offset, lane-constant
// byte offset in one VGPR; issue point pinned by asm volatile.
__device__ __forceinline__ void gload_pair(f32x4& a, f32x4& b, const float* sbase, int voff) {
    asm volatile("global_load_dwordx4 %0, %2, %3\n\t"
                 "global_load_dwordx4 %1, %2, %3 offset:16"
                 : "=&v"(a), "=&v"(b) : "v"(voff), "s"(sbase));
}

// Counted waits; "+v" ties give consumers true SSA deps on the wait (rule-#18 safe).
#define WAIT_TIE2(N, a, b) \
    asm volatile("s_waitcnt vmcnt(" #N ")" : "+v"(a), "+v"(b))
#define WAIT_TIE4(N, a, b, c, d) \
    asm volatile("s_waitcnt vmcnt(" #N ")" : "+v"(a), "+v"(b), "+v"(c), "+v"(d))

#define MFMA(a,b,c) __builtin_amdgcn_mfma_f32_16x16x32_bf16((a),(b),(c),0,0,0)

// One wave = 16 batches, no LDS, no barriers. MFMA 16x16x32 layouts (validated r2-r6):
// A: lane(q,c) holds A[m=c, k=q*8+e]; B: B[k=q*8+e, n=c]; D: D[m=q*4+r, n=c].
// A-row permutation trick: MFMA0 A rows = W[(m>>2)*8+(m&3)], MFMA1 = +4, so lane (q,c)'s
// D regs hold h_new[q*8+0..7] of batch c == exactly the next step's B fragment in-place.
__global__ __launch_bounds__(64, 1)
void rnn_v7(const float* __restrict__ x,
            const float* __restrict__ h0p,
            const float* __restrict__ W_ih,
            const float* __restrict__ W_hh,
            const float* __restrict__ b_ih,
            const float* __restrict__ b_hh,
            const float* __restrict__ W_out,
            const float* __restrict__ b_out,
            float* __restrict__ out,
            int B, int T)
{
    const int l = threadIdx.x;
    const int q = l >> 4;
    const int c = l & 15;
    const int bglob = blockIdx.x * 16 + c;

    const int rA0 = ((c >> 2) << 3) + (c & 3);   // permuted A-row for MFMA0
    const int rA1 = rA0 + 4;                      // for MFMA1

    // W_hh: split hi+lo (compounding path, keep precise). W_ih: plain bf16
    // (feeds xp only; error is fresh each step, non-compounding).
    bf16x8 Whh0h, Whh0l, Whh1h, Whh1l, Wih0, Wih1;
    {
        const f32x4* p;
        p = (const f32x4*)(W_hh + rA0 * HD + q * 8); split_frag(p[0], p[1], Whh0h, Whh0l);
        p = (const f32x4*)(W_hh + rA1 * HD + q * 8); split_frag(p[0], p[1], Whh1h, Whh1l);
        p = (const f32x4*)(W_ih + rA0 * HD + q * 8); Wih0 = to_bf16_frag(p[0], p[1]);
        p = (const f32x4*)(W_ih + rA1 * HD + q * 8); Wih1 = to_bf16_frag(p[0], p[1]);
    }

    f32x4 bias0, bias1;
#pragma unroll
    for (int r = 0; r < 4; ++r) {
        bias0[r] = b_ih[q*8 + r]     + b_hh[q*8 + r];
        bias1[r] = b_ih[q*8 + 4 + r] + b_hh[q*8 + 4 + r];
    }

    // h0 -> plain bf16 B fragment (one-time rounding)
    bf16x8 h_bf;
    {
        const f32x4* p = (const f32x4*)(h0p + (size_t)bglob * HD + q * 8);
        h_bf = to_bf16_frag(p[0], p[1]);
    }

    // lane-constant byte offset; uniform time offset lives in the SGPR base
    const int voff = (int)(((size_t)bglob * T * HD + q * 8) * 4);

    f32x4 xa[DP], xb[DP];
#pragma unroll
    for (int s = 0; s < DP; ++s)
        gload_pair(xa[s], xb[s], x + (size_t)s * HD, voff);

    // xp parity regs: xpA = next even step, xpB = next odd step (2-step slack)
    f32x4 xpA0, xpA1, xpB0, xpB1;
    {
        WAIT_TIE2(22, xa[0], xb[0]);                  // 24 issued, complete pair 0
        bf16x8 xbf = to_bf16_frag(xa[0], xb[0]);
        xpA0 = MFMA(Wih0, xbf, bias0);
        xpA1 = MFMA(Wih1, xbf, bias1);
    }
    {
        WAIT_TIE2(20, xa[1], xb[1]);                  // complete pair 1
        bf16x8 xbf = to_bf16_frag(xa[1], xb[1]);
        xpB0 = MFMA(Wih0, xbf, bias0);
        xpB1 = MFMA(Wih1, xbf, bias1);
    }

    f32x4 hA = {0,0,0,0}, hB = {0,0,0,0};

    // Steady-state ledger (per 2-step group at even t): enter with pairs
    // x[t+2..t+11] in flight (20 loads); issue pairs x[t+12],x[t+13] -> 24;
    // wait vmcnt(20) completes pairs x[t+2],x[t+3]. Lookahead 10 steps.
    for (int t0 = 0; t0 < T; t0 += DP) {
#pragma unroll
        for (int s = 0; s < DP; s += 2) {
            const int t = t0 + s;                     // even
            // ---- recurrence for step t (chain head; consumes xpA) ----
            f32x4 a0 = MFMA(Whh0h, h_bf, xpA0);
            f32x4 a1 = MFMA(Whh1h, h_bf, xpA1);
            a0 = MFMA(Whh0l, h_bf, a0);
            a1 = MFMA(Whh1l, h_bf, a1);

            // ---- refill ring slots s, s+1 with x[t+12], x[t+13] (clamped) ----
            int k1 = t + DP;     k1 = (k1 < T) ? k1 : (T - 1);
            int k2 = t + DP + 1; k2 = (k2 < T) ? k2 : (T - 1);
            gload_pair(xa[s],     xb[s],     x + (size_t)k1 * HD, voff);
            gload_pair(xa[s + 1], xb[s + 1], x + (size_t)k2 * HD, voff);

            // ---- wait for x[t+2], x[t+3] ----
            const int s2 = (s + 2) % DP;
            const int s3 = (s + 3) % DP;
            WAIT_TIE4(20, xa[s2], xb[s2], xa[s3], xb[s3]);

            // ---- xp(t+2) into xpA (off-chain; 2 steps of slack) ----
            {
                bf16x8 xbf = to_bf16_frag(xa[s2], xb[s2]);
                xpA0 = MFMA(Wih0, xbf, bias0);
                xpA1 = MFMA(Wih1, xbf, bias1);
            }

            // ---- finish step t: pack then packed relu -> h_bf(t+1) ----
            h_bf = pack4(pk_relu(cvtpk_bf16(a0[0], a0[1])),
                         pk_relu(cvtpk_bf16(a0[2], a0[3])),
                         pk_relu(cvtpk_bf16(a1[0], a1[1])),
                         pk_relu(cvtpk_bf16(a1[2], a1[3])));

            // ---- recurrence for step t+1 (consumes xpB) ----
            f32x4 b0 = MFMA(Whh0h, h_bf, xpB0);
            f32x4 b1 = MFMA(Whh1h, h_bf, xpB1);
            b0 = MFMA(Whh0l, h_bf, b0);
            b1 = MFMA(Whh1l, h_bf, b1);

            // ---- xp(t+3) into xpB ----
            {
                bf16x8 xbf = to_bf16_frag(xa[s3], xb[s3]);
                xpB0 = MFMA(Wih0, xbf, bias0);
                xpB1 = MFMA(Wih1, xbf, bias1);
            }

            // ---- finish step t+1 ----
            h_bf = pack4(pk_relu(cvtpk_bf16(b0[0], b0[1])),
                         pk_relu(cvtpk_bf16(b0[2], b0[3])),
                         pk_relu(cvtpk_bf16(b1[0], b1[1])),
                         pk_relu(cvtpk_bf16(b1[2], b1[3])));
            hA = b0; hB = b1;                         // pre-relu f32 of last step
        }
    }

    // epilogue: f32 relu of the final step (keeps hT/pred at full f32 precision)
#pragma unroll
    for (int r = 0; r < 4; ++r) {
        hA[r] = fmaxf(hA[r], 0.0f);
        hB[r] = fmaxf(hB[r], 0.0f);
    }

    // hT: lane holds units q*8+r (hA) and q*8+4+r (hB) of batch c
    float* outh = out + B + (size_t)bglob * HD;
#pragma unroll
    for (int r = 0; r < 4; ++r) {
        outh[q*8 + r]     = hA[r];
        outh[q*8 + 4 + r] = hB[r];
    }
    // pred[b]: partials in lanes {c, c+16, c+32, c+48}
    float p = 0.0f;
#pragma unroll
    for (int r = 0; r < 4; ++r)
        p += hA[r] * W_out[q*8 + r] + hB[r] * W_out[q*8 + 4 + r];
    p += __shfl_xor(p, 16, 64);
    p += __shfl_xor(p, 32, 64);
    if (q == 0) out[bglob] = p + b_out[0];
}

extern "C" void kernel_launch(void* const* d_in, const int* in_sizes, int n_in,
                              void* d_out, int out_size, void* d_ws, size_t ws_size,
                              hipStream_t stream) {
    const float* x      = (const float*)d_in[0];
    const float* hidden = (const float*)d_in[1];
    const float* W_ih   = (const float*)d_in[2];
    const float* W_hh   = (const float*)d_in[3];
    const float* b_ih   = (const float*)d_in[4];
    const float* b_hh   = (const float*)d_in[5];
    const float* W_out  = (const float*)d_in[6];
    const float* b_out  = (const float*)d_in[7];
    float* out = (float*)d_out;

    const int B = in_sizes[1] / HD;          // hidden is (1, B, H)
    const int T = in_sizes[0] / (B * HD);    // x is (B, T, 32); T=168 = 14*DP

    rnn_v7<<<dim3(B / 16), dim3(64), 0, stream>>>(
        x, hidden, W_ih, W_hh, b_ih, b_hh, W_out, b_out, out, B, T);
}